// Round 1
// baseline (1594.341 us; speedup 1.0000x reference)
//
#include <hip/hip_runtime.h>

// Problem constants (from reference setup_inputs)
constexpr int T  = 26;      // tables
constexpr int N  = 100000;  // rows per table
constexpr int D  = 128;     // embedding dim
constexpr int B  = 16384;   // bags per table
constexpr int BL = 65536;   // B * L (flat indices per table)
constexpr int D4 = D / 4;   // float4 chunks per row = 32

__global__ __launch_bounds__(256) void merged_emb_pool(
    const float* __restrict__ weights,   // [T, N, D]
    const int*   __restrict__ indices,   // [T, BL]
    const int*   __restrict__ offsets,   // [T, B]
    float*       __restrict__ out)       // [T, B, D]
{
    const long gid = (long)blockIdx.x * blockDim.x + threadIdx.x;
    const long bag = gid >> 5;           // / D4
    if (bag >= (long)T * B) return;
    const int d4 = (int)(gid & (D4 - 1));

    const int t = (int)(bag / B);
    const int b = (int)(bag - (long)t * B);

    // Bag boundaries from offsets (general, monotone offsets; last bag ends at BL)
    const int* offs = offsets + (long)t * B;
    const int start = offs[b];
    const int end   = (b == B - 1) ? BL : offs[b + 1];

    const int*    ibase = indices + (long)t * BL;
    const float4* wbase = reinterpret_cast<const float4*>(weights + (long)t * N * D) + d4;

    float4 acc = make_float4(0.f, 0.f, 0.f, 0.f);

    int l = start;
    // Unroll-by-4: load all indices first, then issue 4 independent row gathers
    for (; l + 4 <= end; l += 4) {
        const int i0 = ibase[l];
        const int i1 = ibase[l + 1];
        const int i2 = ibase[l + 2];
        const int i3 = ibase[l + 3];
        const float4 v0 = wbase[(long)i0 * D4];
        const float4 v1 = wbase[(long)i1 * D4];
        const float4 v2 = wbase[(long)i2 * D4];
        const float4 v3 = wbase[(long)i3 * D4];
        acc.x += v0.x + v1.x + v2.x + v3.x;
        acc.y += v0.y + v1.y + v2.y + v3.y;
        acc.z += v0.z + v1.z + v2.z + v3.z;
        acc.w += v0.w + v1.w + v2.w + v3.w;
    }
    for (; l < end; ++l) {
        const int i0 = ibase[l];
        const float4 v0 = wbase[(long)i0 * D4];
        acc.x += v0.x; acc.y += v0.y; acc.z += v0.z; acc.w += v0.w;
    }

    reinterpret_cast<float4*>(out)[bag * D4 + d4] = acc;
}

extern "C" void kernel_launch(void* const* d_in, const int* in_sizes, int n_in,
                              void* d_out, int out_size, void* d_ws, size_t ws_size,
                              hipStream_t stream) {
    const float* weights = (const float*)d_in[0];
    const int*   indices = (const int*)d_in[1];
    const int*   offsets = (const int*)d_in[2];
    float*       out     = (float*)d_out;

    const long total_threads = (long)T * B * D4;   // 13,631,488
    const int  block = 256;
    const long grid  = (total_threads + block - 1) / block;  // 53,248

    merged_emb_pool<<<(dim3)(unsigned)grid, block, 0, stream>>>(weights, indices, offsets, out);
}